// Round 7
// baseline (560.835 us; speedup 1.0000x reference)
//
#include <hip/hip_runtime.h>

#define D_MODEL 768
#define NHEADS 12
#define DEPTH 64
#define SEQ 2048
#define NROWS 4096   // B*S

typedef float f32x4 __attribute__((ext_vector_type(4)));
typedef short bf16x8 __attribute__((ext_vector_type(8)));

#define MFMA16(a, b, c) __builtin_amdgcn_mfma_f32_16x16x32_bf16((a), (b), (c), 0, 0, 0)

// fp32 -> bf16 with round-to-nearest-even
__device__ __forceinline__ short f2bf(float f) {
    union { float f; unsigned u; } v; v.f = f;
    unsigned r = (v.u + 0x7FFFu + ((v.u >> 16) & 1u)) >> 16;
    return (short)r;
}
// pack two f32 -> one dword of 2 bf16 (low = a), single instruction
__device__ __forceinline__ unsigned cvtpk(float a, float b) {
    unsigned r;
    asm("v_cvt_pk_bf16_f32 %0, %1, %2" : "=v"(r) : "v"(a), "v"(b));
    return r;
}

// ---------------------------------------------------------------------------
// Kernel W: transpose + convert the four weight matrices to bf16.
// wt[i][n][k] = W_i[k][n]
// ---------------------------------------------------------------------------
__global__ __launch_bounds__(256) void wtrans_kernel(
    const float* __restrict__ wq, const float* __restrict__ wk,
    const float* __restrict__ wv, const float* __restrict__ wo,
    short* __restrict__ wt)
{
    __shared__ float tile[32][33];
    int wi = blockIdx.z;
    const float* W = (wi == 0) ? wq : (wi == 1) ? wk : (wi == 2) ? wv : wo;
    short* out = wt + wi * D_MODEL * D_MODEL;
    int k0 = blockIdx.x * 32, n0 = blockIdx.y * 32;
    int t = threadIdx.x;
    int tx = t & 31, ty = t >> 5;  // ty in 0..7
#pragma unroll
    for (int i = 0; i < 4; i++) {
        int kk = ty + i * 8;
        tile[kk][tx] = W[(k0 + kk) * D_MODEL + n0 + tx];
    }
    __syncthreads();
#pragma unroll
    for (int i = 0; i < 4; i++) {
        int nn = ty + i * 8;
        out[(n0 + nn) * D_MODEL + k0 + tx] = f2bf(tile[tx][nn]);
    }
}

// ---------------------------------------------------------------------------
// Kernel A: fused QKV projection GEMM.  z=0: Q (pre-scaled by 0.125*log2(e)),
// z=1: K, z=2: V (written transposed as vt[b,h,d,s]).
// ---------------------------------------------------------------------------
__global__ __launch_bounds__(256) void qkv_gemm(
    const float* __restrict__ inq, const float* __restrict__ ink, const float* __restrict__ inv,
    const short* __restrict__ wt,
    const float* __restrict__ bq, const float* __restrict__ bk, const float* __restrict__ bv,
    short* __restrict__ qh, short* __restrict__ kh, short* __restrict__ vt)
{
    int z = blockIdx.z;
    const float* A    = (z == 0) ? inq : (z == 1) ? ink : inv;
    const short* Bw   = wt + z * D_MODEL * D_MODEL;
    const float* bias = (z == 0) ? bq : (z == 1) ? bk : bv;

    int m0 = blockIdx.x * 64, n0 = blockIdx.y * 64;
    int lane = threadIdx.x & 63, w = threadIdx.x >> 6;
    int r = lane & 15, h = lane >> 4;

    f32x4 acc[4] = {};
    const float* arow = A + (m0 + 16 * w + r) * D_MODEL;

    for (int k0 = 0; k0 < D_MODEL; k0 += 32) {
        float4 a0 = *(const float4*)(arow + k0 + 8 * h);
        float4 a1 = *(const float4*)(arow + k0 + 8 * h + 4);
        bf16x8 af;
        af[0] = f2bf(a0.x); af[1] = f2bf(a0.y); af[2] = f2bf(a0.z); af[3] = f2bf(a0.w);
        af[4] = f2bf(a1.x); af[5] = f2bf(a1.y); af[6] = f2bf(a1.z); af[7] = f2bf(a1.w);
#pragma unroll
        for (int nt = 0; nt < 4; nt++) {
            bf16x8 bfr = *(const bf16x8*)(Bw + (n0 + 16 * nt + r) * D_MODEL + k0 + 8 * h);
            acc[nt] = MFMA16(af, bfr, acc[nt]);
        }
    }

#pragma unroll
    for (int nt = 0; nt < 4; nt++) {
        int col = n0 + 16 * nt + r;
        float bsv = bias[col];
        int hh = col >> 6, dd = col & 63;
        if (z == 2) {
            int m = m0 + 16 * w + 4 * h;     // 4 consecutive rows (s)
            int b = m >> 11, s = m & 2047;
            short4 pk;
            pk.x = f2bf(acc[nt][0] + bsv);
            pk.y = f2bf(acc[nt][1] + bsv);
            pk.z = f2bf(acc[nt][2] + bsv);
            pk.w = f2bf(acc[nt][3] + bsv);
            *(short4*)(vt + ((b * NHEADS + hh) * DEPTH + dd) * SEQ + s) = pk;
        } else {
            float scl = (z == 0) ? 0.18033688011112042f : 1.0f;  // 0.125*log2(e)
            short* dst = (z == 0) ? qh : kh;
#pragma unroll
            for (int rr = 0; rr < 4; rr++) {
                int m = m0 + 16 * w + 4 * h + rr;
                int b = m >> 11, s = m & 2047;
                dst[((b * NHEADS + hh) * SEQ + s) * DEPTH + dd] = f2bf((acc[nt][rr] + bsv) * scl);
            }
        }
    }
}

// ---------------------------------------------------------------------------
// Kernel B1: attn_pv — fused single pass, NO global stores in the loop.
// Grid 1536 (XCD-pinned, 3 heads/XCD). Block = 32 q-rows, 8 waves =
// 2 q-subtiles x 4 k-quarters. Swapped mfma(K,Q): lane owns q-row q=lane&15.
// Accumulates l (unnormalized) and O (PV with unnormalized bf16 P via the
// permuted-contraction V loads). Epilogue: merge across k-quarters, scale by
// rl, write ctx; write rlbuf for the store kernel.
// ---------------------------------------------------------------------------
__global__ __launch_bounds__(512) void attn_pv_kernel(
    const short* __restrict__ qh, const short* __restrict__ kh, const short* __restrict__ vt,
    float* __restrict__ rlbuf, short* __restrict__ ctx)
{
    __shared__ float sml[2][4][16];
    __shared__ float olds[2][3][64][16];   // O partials from ks=1..3

    int wgid = blockIdx.x;
    int xcd = wgid & 7;
    int idx = wgid >> 3;            // 0..191
    int bh = xcd * 3 + (idx >> 6);  // 3 heads per XCD
    int q0 = (idx & 63) * 32;

    int lane = threadIdx.x & 63, w = threadIdx.x >> 6;
    int wq = w >> 2, ks = w & 3;    // q-subtile (16 rows), k-quarter (512)
    int r = lane & 15, h = lane >> 4;
    int qbase = q0 + 16 * wq;
    int kstart = ks * (SEQ / 4), kend = kstart + SEQ / 4;

    const short* Qp = qh + ((long)bh * SEQ + qbase) * DEPTH;
    const short* Kp = kh + (long)bh * SEQ * DEPTH;
    const short* Vp = vt + (long)bh * DEPTH * SEQ;

    bf16x8 qf0 = *(const bf16x8*)(Qp + r * DEPTH + 8 * h);
    bf16x8 qf1 = *(const bf16x8*)(Qp + r * DEPTH + 32 + 8 * h);

    f32x4 o[4] = {};
    float l = 0.f;

    for (int k0 = kstart; k0 < kend; k0 += 32) {
        const short* kr0 = Kp + (k0 + r) * DEPTH + 8 * h;
        const short* kr1 = kr0 + 16 * DEPTH;
        bf16x8 a0 = *(const bf16x8*)(kr0);
        bf16x8 a1 = *(const bf16x8*)(kr0 + 32);
        bf16x8 b0 = *(const bf16x8*)(kr1);
        bf16x8 b1 = *(const bf16x8*)(kr1 + 32);
        f32x4 s0 = {}, s1 = {};
        s0 = MFMA16(a0, qf0, s0);
        s1 = MFMA16(b0, qf0, s1);
        s0 = MFMA16(a1, qf1, s0);
        s1 = MFMA16(b1, qf1, s1);

        // unnormalized p for q=r at k = k0+4h+rr (p0..p3), k0+16+4h+rr (p4..p7)
        float p0 = exp2f(s0[0]), p1 = exp2f(s0[1]);
        float p2 = exp2f(s0[2]), p3 = exp2f(s0[3]);
        float p4 = exp2f(s1[0]), p5 = exp2f(s1[1]);
        float p6 = exp2f(s1[2]), p7 = exp2f(s1[3]);
        l += (p0 + p1) + (p2 + p3) + (p4 + p5) + (p6 + p7);

        // pack P in NATIVE k-slot order; same permutation applied to V below.
        union { unsigned u[4]; bf16x8 v; } pa;
        pa.u[0] = cvtpk(p0, p1); pa.u[1] = cvtpk(p2, p3);
        pa.u[2] = cvtpk(p4, p5); pa.u[3] = cvtpk(p6, p7);

#pragma unroll
        for (int nt = 0; nt < 4; nt++) {
            const short* vrow = Vp + (16 * nt + r) * SEQ;   // vt[d = 16nt + r][*]
            union { short4 s4[2]; bf16x8 v; } vf;
            vf.s4[0] = *(const short4*)(vrow + k0 + 4 * h);
            vf.s4[1] = *(const short4*)(vrow + k0 + 16 + 4 * h);
            o[nt] = MFMA16(vf.v, pa.v, o[nt]);   // D[d' = 4h+rr][q = lane&15]
        }
    }

    l += __shfl_xor(l, 16);
    l += __shfl_xor(l, 32);
    if (lane < 16) sml[wq][ks][lane] = l;
    if (ks != 0) {
#pragma unroll
        for (int nt = 0; nt < 4; nt++)
            *(f32x4*)&olds[wq][ks - 1][lane][nt * 4] = o[nt];
    }
    __syncthreads();
    if (ks == 0) {
        float rl = 1.0f / (sml[wq][0][r] + sml[wq][1][r] + sml[wq][2][r] + sml[wq][3][r]);
        if (lane < 16)
            rlbuf[bh * SEQ + qbase + lane] = rl;   // lane == r here
        int b = bh / NHEADS, head = bh % NHEADS;
        long crow = ((long)(b * SEQ + qbase + r)) * D_MODEL + head * DEPTH;
#pragma unroll
        for (int nt = 0; nt < 4; nt++) {
            f32x4 o1 = *(const f32x4*)&olds[wq][0][lane][nt * 4];
            f32x4 o2 = *(const f32x4*)&olds[wq][1][lane][nt * 4];
            f32x4 o3 = *(const f32x4*)&olds[wq][2][lane][nt * 4];
            float v0 = (o[nt][0] + o1[0] + o2[0] + o3[0]) * rl;
            float v1 = (o[nt][1] + o1[1] + o2[1] + o3[1]) * rl;
            float v2 = (o[nt][2] + o1[2] + o2[2] + o3[2]) * rl;
            float v3 = (o[nt][3] + o1[3] + o2[3] + o3[3]) * rl;
            *(unsigned*)&ctx[crow + 16 * nt + 4 * h]     = cvtpk(v0, v1);
            *(unsigned*)&ctx[crow + 16 * nt + 4 * h + 2] = cvtpk(v2, v3);
        }
    }
}

// ---------------------------------------------------------------------------
// Kernel B2: attn_store — write the 402 MB attn matrix at full write BW.
// Grid 1536 (XCD-pinned). Block = 32 q-rows, 8 waves = 2 q-subtiles x 4
// column-subchunks. Per 512-col chunk: COMPUTE phase (K loads + swapped MFMA
// + exp2*rl -> LDS, no global stores), barrier, STORE phase (ds_read ->
// 8 back-to-back NT f32x4 stores per wave, each 1KB lane-contiguous; no
// loads -> vmcnt never gates issue). LDS granule-XOR swizzle: write 2-way
// (free), read conflict-free.
// ---------------------------------------------------------------------------
__global__ __launch_bounds__(512) void attn_store_kernel(
    const short* __restrict__ qh, const short* __restrict__ kh,
    const float* __restrict__ rlbuf, float* __restrict__ attn)
{
    __shared__ float plds[32 * 512];   // 64 KB: [32 rows][128 granules x 4]

    int wgid = blockIdx.x;
    int xcd = wgid & 7;
    int idx = wgid >> 3;
    int bh = xcd * 3 + (idx >> 6);
    int q0 = (idx & 63) * 32;

    int lane = threadIdx.x & 63, w = threadIdx.x >> 6;
    int wq = w >> 2, kc = w & 3;    // q-subtile (16 rows), column subchunk (128)
    int r = lane & 15, h = lane >> 4;
    int qbase = q0 + 16 * wq;

    const short* Qp = qh + ((long)bh * SEQ + qbase) * DEPTH;
    const short* Kp = kh + (long)bh * SEQ * DEPTH;

    bf16x8 qf0 = *(const bf16x8*)(Qp + r * DEPTH + 8 * h);
    bf16x8 qf1 = *(const bf16x8*)(Qp + r * DEPTH + 32 + 8 * h);
    float rlv = rlbuf[bh * SEQ + qbase + r];

    int myrow = wq * 16 + r;        // row within block (0..31)
    int rowbase_w = myrow * 512;

    for (int chunk = 0; chunk < 4; chunk++) {
        // ---- compute phase: 4 iterations of 32 cols into LDS ----
#pragma unroll
        for (int kk = 0; kk < 4; kk++) {
            int k0 = chunk * 512 + kc * 128 + kk * 32;
            const short* kr0 = Kp + (k0 + r) * DEPTH + 8 * h;
            const short* kr1 = kr0 + 16 * DEPTH;
            bf16x8 a0 = *(const bf16x8*)(kr0);
            bf16x8 a1 = *(const bf16x8*)(kr0 + 32);
            bf16x8 b0 = *(const bf16x8*)(kr1);
            bf16x8 b1 = *(const bf16x8*)(kr1 + 32);
            f32x4 s0 = {}, s1 = {};
            s0 = MFMA16(a0, qf0, s0);
            s1 = MFMA16(b0, qf0, s1);
            s0 = MFMA16(a1, qf1, s0);
            s1 = MFMA16(b1, qf1, s1);

            f32x4 v0, v1;
            v0[0] = exp2f(s0[0]) * rlv; v0[1] = exp2f(s0[1]) * rlv;
            v0[2] = exp2f(s0[2]) * rlv; v0[3] = exp2f(s0[3]) * rlv;
            v1[0] = exp2f(s1[0]) * rlv; v1[1] = exp2f(s1[1]) * rlv;
            v1[2] = exp2f(s1[2]) * rlv; v1[3] = exp2f(s1[3]) * rlv;

            // logical granule within row: G0 covers cols k0+4h.., G1 = +16
            int G0 = kc * 32 + kk * 8 + h;
            int G1 = G0 + 4;
            *(f32x4*)&plds[rowbase_w + ((G0 ^ (r & 7)) << 2)] = v0;
            *(f32x4*)&plds[rowbase_w + ((G1 ^ (r & 7)) << 2)] = v1;
        }
        __syncthreads();

        // ---- store phase: wave w owns rows 4w..4w+3; 1KB contiguous/instr ----
#pragma unroll
        for (int rr = 0; rr < 4; rr++) {
            int R = w * 4 + rr;
            float* arow = attn + ((long)(bh * SEQ + q0 + R)) * SEQ + chunk * 512;
            int rbase = R * 512;
#pragma unroll
            for (int i0 = 0; i0 < 2; i0++) {
                int g = i0 * 64 + lane;
                f32x4 val = *(const f32x4*)&plds[rbase + (((g ^ (R & 7)) & 127) << 2)];
                __builtin_nontemporal_store(val, (f32x4*)(arow + g * 4));
            }
        }
        __syncthreads();
    }
}

// ---------------------------------------------------------------------------
// Kernel C: output projection  out = ctx @ wo + bo  (fp32 out)
// ---------------------------------------------------------------------------
__global__ __launch_bounds__(256) void out_gemm(
    const short* __restrict__ ctx, const short* __restrict__ wt3,
    const float* __restrict__ bo, float* __restrict__ out)
{
    int m0 = blockIdx.x * 64, n0 = blockIdx.y * 64;
    int lane = threadIdx.x & 63, w = threadIdx.x >> 6;
    int r = lane & 15, h = lane >> 4;

    f32x4 acc[4] = {};
    const short* arow = ctx + (m0 + 16 * w + r) * D_MODEL;

    for (int k0 = 0; k0 < D_MODEL; k0 += 32) {
        bf16x8 af = *(const bf16x8*)(arow + k0 + 8 * h);
#pragma unroll
        for (int nt = 0; nt < 4; nt++) {
            bf16x8 bfr = *(const bf16x8*)(wt3 + (n0 + 16 * nt + r) * D_MODEL + k0 + 8 * h);
            acc[nt] = MFMA16(af, bfr, acc[nt]);
        }
    }
#pragma unroll
    for (int nt = 0; nt < 4; nt++) {
        int col = n0 + 16 * nt + r;
        float bsv = bo[col];
#pragma unroll
        for (int rr = 0; rr < 4; rr++) {
            int m = m0 + 16 * w + 4 * h + rr;
            out[(long)m * D_MODEL + col] = acc[nt][rr] + bsv;
        }
    }
}

// ---------------------------------------------------------------------------
extern "C" void kernel_launch(void* const* d_in, const int* in_sizes, int n_in,
                              void* d_out, int out_size, void* d_ws, size_t ws_size,
                              hipStream_t stream)
{
    const float* v  = (const float*)d_in[0];
    const float* k  = (const float*)d_in[1];
    const float* q  = (const float*)d_in[2];
    const float* wq = (const float*)d_in[3];
    const float* bq = (const float*)d_in[4];
    const float* wk = (const float*)d_in[5];
    const float* bk = (const float*)d_in[6];
    const float* wv = (const float*)d_in[7];
    const float* bv = (const float*)d_in[8];
    const float* wo = (const float*)d_in[9];
    const float* bo = (const float*)d_in[10];

    char* ws = (char*)d_ws;
    const size_t WT_BYTES  = (size_t)4 * D_MODEL * D_MODEL * 2;    // 4.7 MB
    const size_t HB_BYTES  = (size_t)2 * NHEADS * SEQ * DEPTH * 2; // 6.3 MB
    const size_t CTX_BYTES = (size_t)NROWS * D_MODEL * 2;          // 6.3 MB
    short* wt  = (short*)(ws);
    short* qh  = (short*)(ws + WT_BYTES);
    short* kh  = (short*)(ws + WT_BYTES + HB_BYTES);
    short* vt  = (short*)(ws + WT_BYTES + 2 * HB_BYTES);
    short* ctx = (short*)(ws + WT_BYTES + 3 * HB_BYTES);
    float* rlb = (float*)(ws + WT_BYTES + 3 * HB_BYTES + CTX_BYTES);

    float* out  = (float*)d_out;
    float* attn = (float*)d_out + (size_t)NROWS * D_MODEL;

    wtrans_kernel<<<dim3(24, 24, 4), dim3(256), 0, stream>>>(wq, wk, wv, wo, wt);
    qkv_gemm<<<dim3(64, 12, 3), dim3(256), 0, stream>>>(q, k, v, wt, bq, bk, bv, qh, kh, vt);
    attn_pv_kernel<<<dim3(1536), dim3(512), 0, stream>>>(qh, kh, vt, rlb, ctx);
    attn_store_kernel<<<dim3(1536), dim3(512), 0, stream>>>(qh, kh, rlb, attn);
    out_gemm<<<dim3(64, 12), dim3(256), 0, stream>>>(ctx, wt + 3 * D_MODEL * D_MODEL, bo, out);
}

// Round 8
// 474.995 us; speedup vs baseline: 1.1807x; 1.1807x over previous
//
#include <hip/hip_runtime.h>

#define D_MODEL 768
#define NHEADS 12
#define DEPTH 64
#define SEQ 2048
#define NROWS 4096   // B*S

typedef float f32x4 __attribute__((ext_vector_type(4)));
typedef short bf16x8 __attribute__((ext_vector_type(8)));

#define MFMA16(a, b, c) __builtin_amdgcn_mfma_f32_16x16x32_bf16((a), (b), (c), 0, 0, 0)

// fp32 -> bf16 with round-to-nearest-even
__device__ __forceinline__ short f2bf(float f) {
    union { float f; unsigned u; } v; v.f = f;
    unsigned r = (v.u + 0x7FFFu + ((v.u >> 16) & 1u)) >> 16;
    return (short)r;
}
// pack two f32 -> one dword of 2 bf16 (low = a), single instruction
__device__ __forceinline__ unsigned cvtpk(float a, float b) {
    unsigned r;
    asm("v_cvt_pk_bf16_f32 %0, %1, %2" : "=v"(r) : "v"(a), "v"(b));
    return r;
}

struct KF { bf16x8 a0, a1, b0, b1; };          // 16 VGPR
struct VF { short4 x[8]; };                     // 16 VGPR

__device__ __forceinline__ KF loadK(const short* __restrict__ Kp, int k0, int r, int h) {
    KF f;
    const short* kr0 = Kp + (k0 + r) * DEPTH + 8 * h;
    const short* kr1 = kr0 + 16 * DEPTH;
    f.a0 = *(const bf16x8*)(kr0);
    f.a1 = *(const bf16x8*)(kr0 + 32);
    f.b0 = *(const bf16x8*)(kr1);
    f.b1 = *(const bf16x8*)(kr1 + 32);
    return f;
}
// vt blocked layout: [bh][s>>5][d][32]; per nt two 8B loads at (4h, 16+4h)
__device__ __forceinline__ VF loadV(const short* __restrict__ Vb, int k0, int r, int h) {
    VF f;
    const short* blk = Vb + (k0 >> 5) * (DEPTH * 32) + 4 * h;
#pragma unroll
    for (int nt = 0; nt < 4; nt++) {
        const short* row = blk + (16 * nt + r) * 32;
        f.x[2 * nt]     = *(const short4*)(row);
        f.x[2 * nt + 1] = *(const short4*)(row + 16);
    }
    return f;
}

// ---------------------------------------------------------------------------
// Kernel W: transpose + convert the four weight matrices to bf16.
// ---------------------------------------------------------------------------
__global__ __launch_bounds__(256) void wtrans_kernel(
    const float* __restrict__ wq, const float* __restrict__ wk,
    const float* __restrict__ wv, const float* __restrict__ wo,
    short* __restrict__ wt)
{
    __shared__ float tile[32][33];
    int wi = blockIdx.z;
    const float* W = (wi == 0) ? wq : (wi == 1) ? wk : (wi == 2) ? wv : wo;
    short* out = wt + wi * D_MODEL * D_MODEL;
    int k0 = blockIdx.x * 32, n0 = blockIdx.y * 32;
    int t = threadIdx.x;
    int tx = t & 31, ty = t >> 5;
#pragma unroll
    for (int i = 0; i < 4; i++) {
        int kk = ty + i * 8;
        tile[kk][tx] = W[(k0 + kk) * D_MODEL + n0 + tx];
    }
    __syncthreads();
#pragma unroll
    for (int i = 0; i < 4; i++) {
        int nn = ty + i * 8;
        out[(n0 + nn) * D_MODEL + k0 + tx] = f2bf(tile[tx][nn]);
    }
}

// ---------------------------------------------------------------------------
// Kernel A: fused QKV projection GEMM.  z=0: Q (pre-scaled by 0.125*log2(e)),
// z=1: K, z=2: V (written k-blocked transposed: vt[bh][s>>5][d][s&31]).
// ---------------------------------------------------------------------------
__global__ __launch_bounds__(256) void qkv_gemm(
    const float* __restrict__ inq, const float* __restrict__ ink, const float* __restrict__ inv,
    const short* __restrict__ wt,
    const float* __restrict__ bq, const float* __restrict__ bk, const float* __restrict__ bv,
    short* __restrict__ qh, short* __restrict__ kh, short* __restrict__ vt)
{
    int z = blockIdx.z;
    const float* A    = (z == 0) ? inq : (z == 1) ? ink : inv;
    const short* Bw   = wt + z * D_MODEL * D_MODEL;
    const float* bias = (z == 0) ? bq : (z == 1) ? bk : bv;

    int m0 = blockIdx.x * 64, n0 = blockIdx.y * 64;
    int lane = threadIdx.x & 63, w = threadIdx.x >> 6;
    int r = lane & 15, h = lane >> 4;

    f32x4 acc[4] = {};
    const float* arow = A + (m0 + 16 * w + r) * D_MODEL;

    for (int k0 = 0; k0 < D_MODEL; k0 += 32) {
        float4 a0 = *(const float4*)(arow + k0 + 8 * h);
        float4 a1 = *(const float4*)(arow + k0 + 8 * h + 4);
        bf16x8 af;
        af[0] = f2bf(a0.x); af[1] = f2bf(a0.y); af[2] = f2bf(a0.z); af[3] = f2bf(a0.w);
        af[4] = f2bf(a1.x); af[5] = f2bf(a1.y); af[6] = f2bf(a1.z); af[7] = f2bf(a1.w);
#pragma unroll
        for (int nt = 0; nt < 4; nt++) {
            bf16x8 bfr = *(const bf16x8*)(Bw + (n0 + 16 * nt + r) * D_MODEL + k0 + 8 * h);
            acc[nt] = MFMA16(af, bfr, acc[nt]);
        }
    }

#pragma unroll
    for (int nt = 0; nt < 4; nt++) {
        int col = n0 + 16 * nt + r;
        float bsv = bias[col];
        int hh = col >> 6, dd = col & 63;
        if (z == 2) {
            int m = m0 + 16 * w + 4 * h;     // 4 consecutive rows (s)
            int b = m >> 11, s = m & 2047;
            short4 pk;
            pk.x = f2bf(acc[nt][0] + bsv);
            pk.y = f2bf(acc[nt][1] + bsv);
            pk.z = f2bf(acc[nt][2] + bsv);
            pk.w = f2bf(acc[nt][3] + bsv);
            // blocked: [bh][s>>5][d][s&31]
            long off = (((long)(b * NHEADS + hh) * 64 + (s >> 5)) * DEPTH + dd) * 32 + (s & 31);
            *(short4*)(vt + off) = pk;
        } else {
            float scl = (z == 0) ? 0.18033688011112042f : 1.0f;  // 0.125*log2(e)
            short* dst = (z == 0) ? qh : kh;
#pragma unroll
            for (int rr = 0; rr < 4; rr++) {
                int m = m0 + 16 * w + 4 * h + rr;
                int b = m >> 11, s = m & 2047;
                dst[((b * NHEADS + hh) * SEQ + s) * DEPTH + dd] = f2bf((acc[nt][rr] + bsv) * scl);
            }
        }
    }
}

// ---------------------------------------------------------------------------
// Kernel B1: attn_pv — fused single pass with REGISTER DOUBLE-BUFFERING.
// All 12 loads of iteration i+1 issue before iteration i's compute; the
// compiler needs ~100 VGPR to hold cur+nxt K/V fragments -> loads overlap
// compute instead of serializing (r7 showed VGPR=36 forced serial loads).
// ---------------------------------------------------------------------------
__global__ __launch_bounds__(512) void attn_pv_kernel(
    const short* __restrict__ qh, const short* __restrict__ kh, const short* __restrict__ vt,
    float* __restrict__ rlbuf, short* __restrict__ ctx)
{
    __shared__ float sml[2][4][16];
    __shared__ float olds[2][3][64][16];

    int wgid = blockIdx.x;
    int xcd = wgid & 7;
    int idx = wgid >> 3;
    int bh = xcd * 3 + (idx >> 6);
    int q0 = (idx & 63) * 32;

    int lane = threadIdx.x & 63, w = threadIdx.x >> 6;
    int wq = w >> 2, ks = w & 3;
    int r = lane & 15, h = lane >> 4;
    int qbase = q0 + 16 * wq;
    int kstart = ks * (SEQ / 4), kend = kstart + SEQ / 4;

    const short* Qp = qh + ((long)bh * SEQ + qbase) * DEPTH;
    const short* Kp = kh + (long)bh * SEQ * DEPTH;
    const short* Vb = vt + (long)bh * (64 * DEPTH * 32);   // blocked V base

    bf16x8 qf0 = *(const bf16x8*)(Qp + r * DEPTH + 8 * h);
    bf16x8 qf1 = *(const bf16x8*)(Qp + r * DEPTH + 32 + 8 * h);

    f32x4 o[4] = {};
    float l = 0.f;

    KF kc_ = loadK(Kp, kstart, r, h);
    VF vc  = loadV(Vb, kstart, r, h);

    for (int k0 = kstart; k0 < kend; k0 += 32) {
        int kn = (k0 + 32 < kend) ? (k0 + 32) : kstart;   // last prefetch is dummy
        KF kn_ = loadK(Kp, kn, r, h);
        VF vn  = loadV(Vb, kn, r, h);

        f32x4 s0 = {}, s1 = {};
        s0 = MFMA16(kc_.a0, qf0, s0);
        s1 = MFMA16(kc_.b0, qf0, s1);
        s0 = MFMA16(kc_.a1, qf1, s0);
        s1 = MFMA16(kc_.b1, qf1, s1);

        float p0 = exp2f(s0[0]), p1 = exp2f(s0[1]);
        float p2 = exp2f(s0[2]), p3 = exp2f(s0[3]);
        float p4 = exp2f(s1[0]), p5 = exp2f(s1[1]);
        float p6 = exp2f(s1[2]), p7 = exp2f(s1[3]);
        l += (p0 + p1) + (p2 + p3) + (p4 + p5) + (p6 + p7);

        union { unsigned u[4]; bf16x8 v; } pa;
        pa.u[0] = cvtpk(p0, p1); pa.u[1] = cvtpk(p2, p3);
        pa.u[2] = cvtpk(p4, p5); pa.u[3] = cvtpk(p6, p7);

#pragma unroll
        for (int nt = 0; nt < 4; nt++) {
            union { short4 s4[2]; bf16x8 v; } vf;
            vf.s4[0] = vc.x[2 * nt];
            vf.s4[1] = vc.x[2 * nt + 1];
            o[nt] = MFMA16(vf.v, pa.v, o[nt]);
        }

        kc_ = kn_;
        vc = vn;
    }

    l += __shfl_xor(l, 16);
    l += __shfl_xor(l, 32);
    if (lane < 16) sml[wq][ks][lane] = l;
    if (ks != 0) {
#pragma unroll
        for (int nt = 0; nt < 4; nt++)
            *(f32x4*)&olds[wq][ks - 1][lane][nt * 4] = o[nt];
    }
    __syncthreads();
    if (ks == 0) {
        float rl = 1.0f / (sml[wq][0][r] + sml[wq][1][r] + sml[wq][2][r] + sml[wq][3][r]);
        if (lane < 16)
            rlbuf[bh * SEQ + qbase + lane] = rl;
        int b = bh / NHEADS, head = bh % NHEADS;
        long crow = ((long)(b * SEQ + qbase + r)) * D_MODEL + head * DEPTH;
#pragma unroll
        for (int nt = 0; nt < 4; nt++) {
            f32x4 o1 = *(const f32x4*)&olds[wq][0][lane][nt * 4];
            f32x4 o2 = *(const f32x4*)&olds[wq][1][lane][nt * 4];
            f32x4 o3 = *(const f32x4*)&olds[wq][2][lane][nt * 4];
            float v0 = (o[nt][0] + o1[0] + o2[0] + o3[0]) * rl;
            float v1 = (o[nt][1] + o1[1] + o2[1] + o3[1]) * rl;
            float v2 = (o[nt][2] + o1[2] + o2[2] + o3[2]) * rl;
            float v3 = (o[nt][3] + o1[3] + o2[3] + o3[3]) * rl;
            *(unsigned*)&ctx[crow + 16 * nt + 4 * h]     = cvtpk(v0, v1);
            *(unsigned*)&ctx[crow + 16 * nt + 4 * h + 2] = cvtpk(v2, v3);
        }
    }
}

// ---------------------------------------------------------------------------
// Kernel B2: attn_store — 256-col chunks (32 KB LDS -> 4 blocks/CU). Per
// chunk: BOTH kk-subtiles' K fragments load up-front (8 loads in flight),
// compute -> swizzled LDS, barrier, pure-NT-store phase (1 KB/instr, no
// loads), barrier.
// ---------------------------------------------------------------------------
__global__ __launch_bounds__(512) void attn_store_kernel(
    const short* __restrict__ qh, const short* __restrict__ kh,
    const float* __restrict__ rlbuf, float* __restrict__ attn)
{
    __shared__ float plds[32 * 256];   // 32 KB: [32 rows][64 granules x f32x4]

    int wgid = blockIdx.x;
    int xcd = wgid & 7;
    int idx = wgid >> 3;
    int bh = xcd * 3 + (idx >> 6);
    int q0 = (idx & 63) * 32;

    int lane = threadIdx.x & 63, w = threadIdx.x >> 6;
    int wq = w >> 2, kc = w & 3;    // q-subtile (16 rows), 64-col subchunk
    int r = lane & 15, h = lane >> 4;
    int qbase = q0 + 16 * wq;

    const short* Qp = qh + ((long)bh * SEQ + qbase) * DEPTH;
    const short* Kp = kh + (long)bh * SEQ * DEPTH;

    bf16x8 qf0 = *(const bf16x8*)(Qp + r * DEPTH + 8 * h);
    bf16x8 qf1 = *(const bf16x8*)(Qp + r * DEPTH + 32 + 8 * h);
    float rlv = rlbuf[bh * SEQ + qbase + r];

    int myrow = wq * 16 + r;
    int rsw = r & 7;

    for (int chunk = 0; chunk < 8; chunk++) {
        int kbase = chunk * 256 + kc * 64;
        KF f0 = loadK(Kp, kbase, r, h);
        KF f1 = loadK(Kp, kbase + 32, r, h);

#pragma unroll
        for (int kk = 0; kk < 2; kk++) {
            KF* f = kk ? &f1 : &f0;
            f32x4 s0 = {}, s1 = {};
            s0 = MFMA16(f->a0, qf0, s0);
            s1 = MFMA16(f->b0, qf0, s1);
            s0 = MFMA16(f->a1, qf1, s0);
            s1 = MFMA16(f->b1, qf1, s1);

            f32x4 v0, v1;
            v0[0] = exp2f(s0[0]) * rlv; v0[1] = exp2f(s0[1]) * rlv;
            v0[2] = exp2f(s0[2]) * rlv; v0[3] = exp2f(s0[3]) * rlv;
            v1[0] = exp2f(s1[0]) * rlv; v1[1] = exp2f(s1[1]) * rlv;
            v1[2] = exp2f(s1[2]) * rlv; v1[3] = exp2f(s1[3]) * rlv;

            int G0 = kc * 16 + kk * 8 + h;   // granule (4 floats) within row
            int G1 = G0 + 4;
            int p0 = (G0 & ~7) | ((G0 & 7) ^ rsw);
            int p1 = (G1 & ~7) | ((G1 & 7) ^ rsw);
            *(f32x4*)&plds[myrow * 256 + p0 * 4] = v0;
            *(f32x4*)&plds[myrow * 256 + p1 * 4] = v1;
        }
        __syncthreads();

        // store phase: wave w owns rows 4w..4w+3; one 1KB NT store per row
#pragma unroll
        for (int rr = 0; rr < 4; rr++) {
            int R = w * 4 + rr;
            float* arow = attn + ((long)(bh * SEQ + q0 + R)) * SEQ + chunk * 256;
            int g = lane;
            int pg = (g & ~7) | ((g & 7) ^ (R & 7));
            f32x4 val = *(const f32x4*)&plds[R * 256 + pg * 4];
            __builtin_nontemporal_store(val, (f32x4*)(arow + g * 4));
        }
        __syncthreads();
    }
}

// ---------------------------------------------------------------------------
// Kernel C: output projection  out = ctx @ wo + bo  (fp32 out)
// ---------------------------------------------------------------------------
__global__ __launch_bounds__(256) void out_gemm(
    const short* __restrict__ ctx, const short* __restrict__ wt3,
    const float* __restrict__ bo, float* __restrict__ out)
{
    int m0 = blockIdx.x * 64, n0 = blockIdx.y * 64;
    int lane = threadIdx.x & 63, w = threadIdx.x >> 6;
    int r = lane & 15, h = lane >> 4;

    f32x4 acc[4] = {};
    const short* arow = ctx + (m0 + 16 * w + r) * D_MODEL;

    for (int k0 = 0; k0 < D_MODEL; k0 += 32) {
        bf16x8 af = *(const bf16x8*)(arow + k0 + 8 * h);
#pragma unroll
        for (int nt = 0; nt < 4; nt++) {
            bf16x8 bfr = *(const bf16x8*)(wt3 + (n0 + 16 * nt + r) * D_MODEL + k0 + 8 * h);
            acc[nt] = MFMA16(af, bfr, acc[nt]);
        }
    }
#pragma unroll
    for (int nt = 0; nt < 4; nt++) {
        int col = n0 + 16 * nt + r;
        float bsv = bo[col];
#pragma unroll
        for (int rr = 0; rr < 4; rr++) {
            int m = m0 + 16 * w + 4 * h + rr;
            out[(long)m * D_MODEL + col] = acc[nt][rr] + bsv;
        }
    }
}

// ---------------------------------------------------------------------------
extern "C" void kernel_launch(void* const* d_in, const int* in_sizes, int n_in,
                              void* d_out, int out_size, void* d_ws, size_t ws_size,
                              hipStream_t stream)
{
    const float* v  = (const float*)d_in[0];
    const float* k  = (const float*)d_in[1];
    const float* q  = (const float*)d_in[2];
    const float* wq = (const float*)d_in[3];
    const float* bq = (const float*)d_in[4];
    const float* wk = (const float*)d_in[5];
    const float* bk = (const float*)d_in[6];
    const float* wv = (const float*)d_in[7];
    const float* bv = (const float*)d_in[8];
    const float* wo = (const float*)d_in[9];
    const float* bo = (const float*)d_in[10];

    char* ws = (char*)d_ws;
    const size_t WT_BYTES  = (size_t)4 * D_MODEL * D_MODEL * 2;    // 4.7 MB
    const size_t HB_BYTES  = (size_t)2 * NHEADS * SEQ * DEPTH * 2; // 6.3 MB
    const size_t CTX_BYTES = (size_t)NROWS * D_MODEL * 2;          // 6.3 MB
    short* wt  = (short*)(ws);
    short* qh  = (short*)(ws + WT_BYTES);
    short* kh  = (short*)(ws + WT_BYTES + HB_BYTES);
    short* vt  = (short*)(ws + WT_BYTES + 2 * HB_BYTES);
    short* ctx = (short*)(ws + WT_BYTES + 3 * HB_BYTES);
    float* rlb = (float*)(ws + WT_BYTES + 3 * HB_BYTES + CTX_BYTES);

    float* out  = (float*)d_out;
    float* attn = (float*)d_out + (size_t)NROWS * D_MODEL;

    wtrans_kernel<<<dim3(24, 24, 4), dim3(256), 0, stream>>>(wq, wk, wv, wo, wt);
    qkv_gemm<<<dim3(64, 12, 3), dim3(256), 0, stream>>>(q, k, v, wt, bq, bk, bv, qh, kh, vt);
    attn_pv_kernel<<<dim3(1536), dim3(512), 0, stream>>>(qh, kh, vt, rlb, ctx);
    attn_store_kernel<<<dim3(1536), dim3(512), 0, stream>>>(qh, kh, rlb, attn);
    out_gemm<<<dim3(64, 12), dim3(256), 0, stream>>>(ctx, wt + 3 * D_MODEL * D_MODEL, bo, out);
}

// Round 9
// 402.554 us; speedup vs baseline: 1.3932x; 1.1800x over previous
//
#include <hip/hip_runtime.h>

#define D_MODEL 768
#define NHEADS 12
#define DEPTH 64
#define SEQ 2048
#define NROWS 4096   // B*S

typedef float f32x4 __attribute__((ext_vector_type(4)));
typedef short bf16x8 __attribute__((ext_vector_type(8)));

#define MFMA16(a, b, c) __builtin_amdgcn_mfma_f32_16x16x32_bf16((a), (b), (c), 0, 0, 0)

// fp32 -> bf16 round-to-nearest-even
__device__ __forceinline__ short f2bf(float f) {
    union { float f; unsigned u; } v; v.f = f;
    unsigned r = (v.u + 0x7FFFu + ((v.u >> 16) & 1u)) >> 16;
    return (short)r;
}
__device__ __forceinline__ unsigned cvtpk(float a, float b) {
    unsigned r;
    asm("v_cvt_pk_bf16_f32 %0, %1, %2" : "=v"(r) : "v"(a), "v"(b));
    return r;
}

struct KF { bf16x8 a0, a1, b0, b1; };          // 16 VGPR
struct VF { short4 x[8]; };                     // 16 VGPR

__device__ __forceinline__ KF loadK(const short* __restrict__ Kp, int k0, int r, int h) {
    KF f;
    const short* kr0 = Kp + (k0 + r) * DEPTH + 8 * h;
    const short* kr1 = kr0 + 16 * DEPTH;
    f.a0 = *(const bf16x8*)(kr0);
    f.a1 = *(const bf16x8*)(kr0 + 32);
    f.b0 = *(const bf16x8*)(kr1);
    f.b1 = *(const bf16x8*)(kr1 + 32);
    return f;
}
// vt blocked layout: [bh][s>>5][d][32]; per nt two 8B loads at (4h, 16+4h)
__device__ __forceinline__ VF loadV(const short* __restrict__ Vb, int k0, int r, int h) {
    VF f;
    const short* blk = Vb + (k0 >> 5) * (DEPTH * 32) + 4 * h;
#pragma unroll
    for (int nt = 0; nt < 4; nt++) {
        const short* row = blk + (16 * nt + r) * 32;
        f.x[2 * nt]     = *(const short4*)(row);
        f.x[2 * nt + 1] = *(const short4*)(row + 16);
    }
    return f;
}

// ---------------------------------------------------------------------------
// Kernel W: transpose + convert the four weight matrices to bf16.
// ---------------------------------------------------------------------------
__global__ __launch_bounds__(256) void wtrans_kernel(
    const float* __restrict__ wq, const float* __restrict__ wk,
    const float* __restrict__ wv, const float* __restrict__ wo,
    short* __restrict__ wt)
{
    __shared__ float tile[32][33];
    int wi = blockIdx.z;
    const float* W = (wi == 0) ? wq : (wi == 1) ? wk : (wi == 2) ? wv : wo;
    short* out = wt + wi * D_MODEL * D_MODEL;
    int k0 = blockIdx.x * 32, n0 = blockIdx.y * 32;
    int t = threadIdx.x;
    int tx = t & 31, ty = t >> 5;
#pragma unroll
    for (int i = 0; i < 4; i++) {
        int kk = ty + i * 8;
        tile[kk][tx] = W[(k0 + kk) * D_MODEL + n0 + tx];
    }
    __syncthreads();
#pragma unroll
    for (int i = 0; i < 4; i++) {
        int nn = ty + i * 8;
        out[(n0 + nn) * D_MODEL + k0 + tx] = f2bf(tile[tx][nn]);
    }
}

// ---------------------------------------------------------------------------
// Kernel A: fused QKV projection GEMM.  z=0: Q (pre-scaled by 0.125*log2(e)),
// z=1: K, z=2: V (k-blocked transposed: vt[bh][s>>5][d][s&31]).
// ---------------------------------------------------------------------------
__global__ __launch_bounds__(256) void qkv_gemm(
    const float* __restrict__ inq, const float* __restrict__ ink, const float* __restrict__ inv,
    const short* __restrict__ wt,
    const float* __restrict__ bq, const float* __restrict__ bk, const float* __restrict__ bv,
    short* __restrict__ qh, short* __restrict__ kh, short* __restrict__ vt)
{
    int z = blockIdx.z;
    const float* A    = (z == 0) ? inq : (z == 1) ? ink : inv;
    const short* Bw   = wt + z * D_MODEL * D_MODEL;
    const float* bias = (z == 0) ? bq : (z == 1) ? bk : bv;

    int m0 = blockIdx.x * 64, n0 = blockIdx.y * 64;
    int lane = threadIdx.x & 63, w = threadIdx.x >> 6;
    int r = lane & 15, h = lane >> 4;

    f32x4 acc[4] = {};
    const float* arow = A + (m0 + 16 * w + r) * D_MODEL;

    for (int k0 = 0; k0 < D_MODEL; k0 += 32) {
        float4 a0 = *(const float4*)(arow + k0 + 8 * h);
        float4 a1 = *(const float4*)(arow + k0 + 8 * h + 4);
        bf16x8 af;
        af[0] = f2bf(a0.x); af[1] = f2bf(a0.y); af[2] = f2bf(a0.z); af[3] = f2bf(a0.w);
        af[4] = f2bf(a1.x); af[5] = f2bf(a1.y); af[6] = f2bf(a1.z); af[7] = f2bf(a1.w);
#pragma unroll
        for (int nt = 0; nt < 4; nt++) {
            bf16x8 bfr = *(const bf16x8*)(Bw + (n0 + 16 * nt + r) * D_MODEL + k0 + 8 * h);
            acc[nt] = MFMA16(af, bfr, acc[nt]);
        }
    }

#pragma unroll
    for (int nt = 0; nt < 4; nt++) {
        int col = n0 + 16 * nt + r;
        float bsv = bias[col];
        int hh = col >> 6, dd = col & 63;
        if (z == 2) {
            int m = m0 + 16 * w + 4 * h;
            int b = m >> 11, s = m & 2047;
            short4 pk;
            pk.x = f2bf(acc[nt][0] + bsv);
            pk.y = f2bf(acc[nt][1] + bsv);
            pk.z = f2bf(acc[nt][2] + bsv);
            pk.w = f2bf(acc[nt][3] + bsv);
            long off = (((long)(b * NHEADS + hh) * 64 + (s >> 5)) * DEPTH + dd) * 32 + (s & 31);
            *(short4*)(vt + off) = pk;
        } else {
            float scl = (z == 0) ? 0.18033688011112042f : 1.0f;  // 0.125*log2(e)
            short* dst = (z == 0) ? qh : kh;
#pragma unroll
            for (int rr = 0; rr < 4; rr++) {
                int m = m0 + 16 * w + 4 * h + rr;
                int b = m >> 11, s = m & 2047;
                dst[((b * NHEADS + hh) * SEQ + s) * DEPTH + dd] = f2bf((acc[nt][rr] + bsv) * scl);
            }
        }
    }
}

// ---------------------------------------------------------------------------
// Kernel B: attention v6 — q-register-blocked (32 q-rows/wave), single kernel.
// Grid 384 (XCD-pinned, 3 heads/XCD; all 3072 waves co-resident). Block =
// 128 q-rows, 512 thr = 4 q-groups x 2 k-halves. Each wave: 2 q-sets of 16,
// so every K/V tile load (12 loads) feeds 16 MFMAs + 32 exp2 — compute per
// iteration now exceeds L2 latency, and a 2-deep register double-buffer
// hides the rest.
// Pass 1: K-only, sum of exp2 per set -> rl (merged across k-halves via LDS).
// Pass 2: recompute QK, NT-store normalized P (fp32), pack pa (cvt_pk),
// shuffle-free PV (permuted-contraction blocked-V loads). Epilogue merges O
// across the two k-half waves via LDS and writes bf16 ctx.
// ---------------------------------------------------------------------------
__global__ __launch_bounds__(512, 2) void attn_kernel(
    const short* __restrict__ qh, const short* __restrict__ kh, const short* __restrict__ vt,
    float* __restrict__ attn, short* __restrict__ ctx)
{
    __shared__ float sml[4][2][2][16];
    __shared__ float olds[4][64][32];   // ksh=1 partials: [wq2][lane][2set x 4nt x f32x4]

    int wgid = blockIdx.x;
    int xcd = wgid & 7;
    int idx = wgid >> 3;             // 0..47
    int bh = xcd * 3 + (idx >> 4);   // 3 heads per XCD
    int q0 = (idx & 15) * 128;

    int lane = threadIdx.x & 63, w = threadIdx.x >> 6;
    int wq2 = w >> 1, ksh = w & 1;   // q-group (32 rows), k-half (1024)
    int r = lane & 15, h = lane >> 4;
    int qbase = q0 + 32 * wq2;
    int kstart = ksh * (SEQ / 2), kend = kstart + SEQ / 2;

    const short* Qp = qh + ((long)bh * SEQ + qbase) * DEPTH;
    const short* Kp = kh + (long)bh * SEQ * DEPTH;
    const short* Vb = vt + (long)bh * (64 * DEPTH * 32);

    bf16x8 qf[2][2];
#pragma unroll
    for (int j = 0; j < 2; j++) {
        qf[j][0] = *(const bf16x8*)(Qp + (16 * j + r) * DEPTH + 8 * h);
        qf[j][1] = *(const bf16x8*)(Qp + (16 * j + r) * DEPTH + 32 + 8 * h);
    }

    // ---- pass 1: K-only, accumulate sum of exp2 per q-set ----
    float l0 = 0.f, l1 = 0.f;
    {
        KF kc_ = loadK(Kp, kstart, r, h);
        for (int k0 = kstart; k0 < kend; k0 += 32) {
            int kn = (k0 + 32 < kend) ? (k0 + 32) : kstart;
            KF kn_ = loadK(Kp, kn, r, h);
#pragma unroll
            for (int j = 0; j < 2; j++) {
                f32x4 s0 = {}, s1 = {};
                s0 = MFMA16(kc_.a0, qf[j][0], s0);
                s1 = MFMA16(kc_.b0, qf[j][0], s1);
                s0 = MFMA16(kc_.a1, qf[j][1], s0);
                s1 = MFMA16(kc_.b1, qf[j][1], s1);
                float sum = exp2f(s0[0]) + exp2f(s0[1]) + exp2f(s0[2]) + exp2f(s0[3])
                          + exp2f(s1[0]) + exp2f(s1[1]) + exp2f(s1[2]) + exp2f(s1[3]);
                if (j == 0) l0 += sum; else l1 += sum;
            }
            kc_ = kn_;
        }
    }
    l0 += __shfl_xor(l0, 16); l0 += __shfl_xor(l0, 32);
    l1 += __shfl_xor(l1, 16); l1 += __shfl_xor(l1, 32);
    if (lane < 16) {
        sml[wq2][ksh][0][lane] = l0;
        sml[wq2][ksh][1][lane] = l1;
    }
    __syncthreads();
    float rl[2];
#pragma unroll
    for (int j = 0; j < 2; j++)
        rl[j] = 1.0f / (sml[wq2][0][j][r] + sml[wq2][1][j][r]);

    // ---- pass 2: recompute QK, NT-store P, PV ----
    f32x4 o[2][4] = {};
    float* arow0 = attn + ((long)(bh * SEQ + qbase + r)) * SEQ;        // set 0 row
    float* arow1 = attn + ((long)(bh * SEQ + qbase + 16 + r)) * SEQ;   // set 1 row

    {
        KF kc_ = loadK(Kp, kstart, r, h);
        VF vc  = loadV(Vb, kstart, r, h);
        for (int k0 = kstart; k0 < kend; k0 += 32) {
            int kn = (k0 + 32 < kend) ? (k0 + 32) : kstart;
            KF kn_ = loadK(Kp, kn, r, h);
            VF vn  = loadV(Vb, kn, r, h);

#pragma unroll
            for (int j = 0; j < 2; j++) {
                f32x4 s0 = {}, s1 = {};
                s0 = MFMA16(kc_.a0, qf[j][0], s0);
                s1 = MFMA16(kc_.b0, qf[j][0], s1);
                s0 = MFMA16(kc_.a1, qf[j][1], s0);
                s1 = MFMA16(kc_.b1, qf[j][1], s1);

                float p0 = exp2f(s0[0]) * rl[j], p1 = exp2f(s0[1]) * rl[j];
                float p2 = exp2f(s0[2]) * rl[j], p3 = exp2f(s0[3]) * rl[j];
                float p4 = exp2f(s1[0]) * rl[j], p5 = exp2f(s1[1]) * rl[j];
                float p6 = exp2f(s1[2]) * rl[j], p7 = exp2f(s1[3]) * rl[j];

                f32x4 st0 = {p0, p1, p2, p3};
                f32x4 st1 = {p4, p5, p6, p7};
                float* arow = j ? arow1 : arow0;
                __builtin_nontemporal_store(st0, (f32x4*)(arow + k0 + 4 * h));
                __builtin_nontemporal_store(st1, (f32x4*)(arow + k0 + 16 + 4 * h));

                union { unsigned u[4]; bf16x8 v; } pa;
                pa.u[0] = cvtpk(p0, p1); pa.u[1] = cvtpk(p2, p3);
                pa.u[2] = cvtpk(p4, p5); pa.u[3] = cvtpk(p6, p7);

#pragma unroll
                for (int nt = 0; nt < 4; nt++) {
                    union { short4 s4[2]; bf16x8 v; } vf;
                    vf.s4[0] = vc.x[2 * nt];
                    vf.s4[1] = vc.x[2 * nt + 1];
                    o[j][nt] = MFMA16(vf.v, pa.v, o[j][nt]);
                }
            }
            kc_ = kn_;
            vc = vn;
        }
    }

    // ---- merge O across the two k-half waves, write ctx ----
    if (ksh == 1) {
#pragma unroll
        for (int j = 0; j < 2; j++)
#pragma unroll
            for (int nt = 0; nt < 4; nt++)
                *(f32x4*)&olds[wq2][lane][(j * 4 + nt) * 4] = o[j][nt];
    }
    __syncthreads();
    if (ksh == 0) {
        int b = bh / NHEADS, head = bh % NHEADS;
#pragma unroll
        for (int j = 0; j < 2; j++) {
            long crow = ((long)(b * SEQ + qbase + 16 * j + r)) * D_MODEL + head * DEPTH;
#pragma unroll
            for (int nt = 0; nt < 4; nt++) {
                f32x4 op = *(const f32x4*)&olds[wq2][lane][(j * 4 + nt) * 4];
                float v0 = o[j][nt][0] + op[0];
                float v1 = o[j][nt][1] + op[1];
                float v2 = o[j][nt][2] + op[2];
                float v3 = o[j][nt][3] + op[3];
                *(unsigned*)&ctx[crow + 16 * nt + 4 * h]     = cvtpk(v0, v1);
                *(unsigned*)&ctx[crow + 16 * nt + 4 * h + 2] = cvtpk(v2, v3);
            }
        }
    }
}

// ---------------------------------------------------------------------------
// Kernel C: output projection  out = ctx @ wo + bo  (fp32 out)
// ---------------------------------------------------------------------------
__global__ __launch_bounds__(256) void out_gemm(
    const short* __restrict__ ctx, const short* __restrict__ wt3,
    const float* __restrict__ bo, float* __restrict__ out)
{
    int m0 = blockIdx.x * 64, n0 = blockIdx.y * 64;
    int lane = threadIdx.x & 63, w = threadIdx.x >> 6;
    int r = lane & 15, h = lane >> 4;

    f32x4 acc[4] = {};
    const short* arow = ctx + (m0 + 16 * w + r) * D_MODEL;

    for (int k0 = 0; k0 < D_MODEL; k0 += 32) {
        bf16x8 af = *(const bf16x8*)(arow + k0 + 8 * h);
#pragma unroll
        for (int nt = 0; nt < 4; nt++) {
            bf16x8 bfr = *(const bf16x8*)(wt3 + (n0 + 16 * nt + r) * D_MODEL + k0 + 8 * h);
            acc[nt] = MFMA16(af, bfr, acc[nt]);
        }
    }
#pragma unroll
    for (int nt = 0; nt < 4; nt++) {
        int col = n0 + 16 * nt + r;
        float bsv = bo[col];
#pragma unroll
        for (int rr = 0; rr < 4; rr++) {
            int m = m0 + 16 * w + 4 * h + rr;
            out[(long)m * D_MODEL + col] = acc[nt][rr] + bsv;
        }
    }
}

// ---------------------------------------------------------------------------
extern "C" void kernel_launch(void* const* d_in, const int* in_sizes, int n_in,
                              void* d_out, int out_size, void* d_ws, size_t ws_size,
                              hipStream_t stream)
{
    const float* v  = (const float*)d_in[0];
    const float* k  = (const float*)d_in[1];
    const float* q  = (const float*)d_in[2];
    const float* wq = (const float*)d_in[3];
    const float* bq = (const float*)d_in[4];
    const float* wk = (const float*)d_in[5];
    const float* bk = (const float*)d_in[6];
    const float* wv = (const float*)d_in[7];
    const float* bv = (const float*)d_in[8];
    const float* wo = (const float*)d_in[9];
    const float* bo = (const float*)d_in[10];

    char* ws = (char*)d_ws;
    const size_t WT_BYTES  = (size_t)4 * D_MODEL * D_MODEL * 2;    // 4.7 MB
    const size_t HB_BYTES  = (size_t)2 * NHEADS * SEQ * DEPTH * 2; // 6.3 MB
    short* wt  = (short*)(ws);
    short* qh  = (short*)(ws + WT_BYTES);
    short* kh  = (short*)(ws + WT_BYTES + HB_BYTES);
    short* vt  = (short*)(ws + WT_BYTES + 2 * HB_BYTES);
    short* ctx = (short*)(ws + WT_BYTES + 3 * HB_BYTES);

    float* out  = (float*)d_out;
    float* attn = (float*)d_out + (size_t)NROWS * D_MODEL;

    wtrans_kernel<<<dim3(24, 24, 4), dim3(256), 0, stream>>>(wq, wk, wv, wo, wt);
    qkv_gemm<<<dim3(64, 12, 3), dim3(256), 0, stream>>>(q, k, v, wt, bq, bk, bv, qh, kh, vt);
    attn_kernel<<<dim3(384), dim3(512), 0, stream>>>(qh, kh, vt, attn, ctx);
    out_gemm<<<dim3(64, 12), dim3(256), 0, stream>>>(ctx, wt + 3 * D_MODEL * D_MODEL, bo, out);
}

// Round 10
// 382.787 us; speedup vs baseline: 1.4651x; 1.0516x over previous
//
#include <hip/hip_runtime.h>

#define D_MODEL 768
#define NHEADS 12
#define DEPTH 64
#define SEQ 2048
#define NROWS 4096   // B*S

typedef float f32x4 __attribute__((ext_vector_type(4)));
typedef short bf16x8 __attribute__((ext_vector_type(8)));
typedef unsigned u32x2 __attribute__((ext_vector_type(2)));
typedef unsigned u32x4 __attribute__((ext_vector_type(4)));

#define MFMA16(a, b, c) __builtin_amdgcn_mfma_f32_16x16x32_bf16((a), (b), (c), 0, 0, 0)

// fp32 -> bf16 round-to-nearest-even
__device__ __forceinline__ short f2bf(float f) {
    union { float f; unsigned u; } v; v.f = f;
    unsigned r = (v.u + 0x7FFFu + ((v.u >> 16) & 1u)) >> 16;
    return (short)r;
}
__device__ __forceinline__ unsigned cvtpk(float a, float b) {
    unsigned r;
    asm("v_cvt_pk_bf16_f32 %0, %1, %2" : "=v"(r) : "v"(a), "v"(b));
    return r;
}

struct KF { bf16x8 a0, a1, b0, b1; };          // 16 VGPR
struct VF { short4 x[8]; };                     // 16 VGPR

__device__ __forceinline__ KF loadK(const short* __restrict__ Kp, int k0, int r, int h) {
    KF f;
    const short* kr0 = Kp + (k0 + r) * DEPTH + 8 * h;
    const short* kr1 = kr0 + 16 * DEPTH;
    f.a0 = *(const bf16x8*)(kr0);
    f.a1 = *(const bf16x8*)(kr0 + 32);
    f.b0 = *(const bf16x8*)(kr1);
    f.b1 = *(const bf16x8*)(kr1 + 32);
    return f;
}
// vt blocked layout: [bh][s>>5][d][32]; per nt two 8B loads at (4h, 16+4h)
__device__ __forceinline__ VF loadV(const short* __restrict__ Vb, int k0, int r, int h) {
    VF f;
    const short* blk = Vb + (k0 >> 5) * (DEPTH * 32) + 4 * h;
#pragma unroll
    for (int nt = 0; nt < 4; nt++) {
        const short* row = blk + (16 * nt + r) * 32;
        f.x[2 * nt]     = *(const short4*)(row);
        f.x[2 * nt + 1] = *(const short4*)(row + 16);
    }
    return f;
}

// ---------------------------------------------------------------------------
// Kernel X: cast the three fp32 inputs to bf16 once (hoists per-k-step
// conversion out of qkv_gemm's inner loop). xb slots: 0=q, 1=k, 2=v.
// ---------------------------------------------------------------------------
__global__ __launch_bounds__(256) void xcast_kernel(
    const float* __restrict__ q, const float* __restrict__ k, const float* __restrict__ v,
    short* __restrict__ xb)
{
    int z = blockIdx.y;
    const float* src = (z == 0) ? q : (z == 1) ? k : v;
    short* dst = xb + (size_t)z * NROWS * D_MODEL;
    int i = (blockIdx.x * 256 + threadIdx.x) * 8;
    float4 f0 = *(const float4*)(src + i);
    float4 f1 = *(const float4*)(src + i + 4);
    u32x4 o;
    o[0] = cvtpk(f0.x, f0.y); o[1] = cvtpk(f0.z, f0.w);
    o[2] = cvtpk(f1.x, f1.y); o[3] = cvtpk(f1.z, f1.w);
    *(u32x4*)(dst + i) = o;
}

// ---------------------------------------------------------------------------
// Kernel W: transpose + convert the four weight matrices to bf16.
// ---------------------------------------------------------------------------
__global__ __launch_bounds__(256) void wtrans_kernel(
    const float* __restrict__ wq, const float* __restrict__ wk,
    const float* __restrict__ wv, const float* __restrict__ wo,
    short* __restrict__ wt)
{
    __shared__ float tile[32][33];
    int wi = blockIdx.z;
    const float* W = (wi == 0) ? wq : (wi == 1) ? wk : (wi == 2) ? wv : wo;
    short* out = wt + wi * D_MODEL * D_MODEL;
    int k0 = blockIdx.x * 32, n0 = blockIdx.y * 32;
    int t = threadIdx.x;
    int tx = t & 31, ty = t >> 5;
#pragma unroll
    for (int i = 0; i < 4; i++) {
        int kk = ty + i * 8;
        tile[kk][tx] = W[(k0 + kk) * D_MODEL + n0 + tx];
    }
    __syncthreads();
#pragma unroll
    for (int i = 0; i < 4; i++) {
        int nn = ty + i * 8;
        out[(n0 + nn) * D_MODEL + k0 + tx] = f2bf(tile[tx][nn]);
    }
}

// ---------------------------------------------------------------------------
// Kernel A: fused QKV projection GEMM (bf16 A from xcast).
// z=0: Q (pre-scaled by 0.125*log2(e)), z=1: K — SWAPPED operand order so
// each lane's D fragment holds 4 consecutive d at fixed s -> 8B stores.
// z=2: V — unswapped, written k-blocked transposed vt[bh][s>>5][d][s&31].
// ---------------------------------------------------------------------------
__global__ __launch_bounds__(256) void qkv_gemm(
    const short* __restrict__ xb, const short* __restrict__ wt,
    const float* __restrict__ bq, const float* __restrict__ bk, const float* __restrict__ bv,
    short* __restrict__ qh, short* __restrict__ kh, short* __restrict__ vt)
{
    int z = blockIdx.z;
    const short* A  = xb + (size_t)z * NROWS * D_MODEL;
    const short* Bw = wt + z * D_MODEL * D_MODEL;

    int m0 = blockIdx.x * 64, n0 = blockIdx.y * 64;
    int lane = threadIdx.x & 63, w = threadIdx.x >> 6;
    int r = lane & 15, h = lane >> 4;
    const short* arow = A + (m0 + 16 * w + r) * D_MODEL;

    f32x4 acc[4] = {};

    if (z == 2) {
        const float* bias = bv;
        for (int k0 = 0; k0 < D_MODEL; k0 += 32) {
            bf16x8 af = *(const bf16x8*)(arow + k0 + 8 * h);
#pragma unroll
            for (int nt = 0; nt < 4; nt++) {
                bf16x8 bfr = *(const bf16x8*)(Bw + (n0 + 16 * nt + r) * D_MODEL + k0 + 8 * h);
                acc[nt] = MFMA16(af, bfr, acc[nt]);   // D: rows=s, cols=d
            }
        }
#pragma unroll
        for (int nt = 0; nt < 4; nt++) {
            int col = n0 + 16 * nt + r;
            float bsv = bias[col];
            int hh = col >> 6, dd = col & 63;
            int m = m0 + 16 * w + 4 * h;
            int b = m >> 11, s = m & 2047;
            short4 pk;
            pk.x = f2bf(acc[nt][0] + bsv);
            pk.y = f2bf(acc[nt][1] + bsv);
            pk.z = f2bf(acc[nt][2] + bsv);
            pk.w = f2bf(acc[nt][3] + bsv);
            long off = (((long)(b * NHEADS + hh) * 64 + (s >> 5)) * DEPTH + dd) * 32 + (s & 31);
            *(short4*)(vt + off) = pk;
        }
    } else {
        const float* bias = (z == 0) ? bq : bk;
        float scl = (z == 0) ? 0.18033688011112042f : 1.0f;  // 0.125*log2(e)
        short* dst = (z == 0) ? qh : kh;
        for (int k0 = 0; k0 < D_MODEL; k0 += 32) {
            bf16x8 af = *(const bf16x8*)(arow + k0 + 8 * h);
#pragma unroll
            for (int nt = 0; nt < 4; nt++) {
                bf16x8 bfr = *(const bf16x8*)(Bw + (n0 + 16 * nt + r) * D_MODEL + k0 + 8 * h);
                acc[nt] = MFMA16(bfr, af, acc[nt]);   // SWAPPED: rows=d, cols=s
            }
        }
        int hh = n0 >> 6;                  // head fixed per block
        int m = m0 + 16 * w + r;
        int b = m >> 11, s = m & 2047;
        long rowoff = ((long)(b * NHEADS + hh) * SEQ + s) * DEPTH;
#pragma unroll
        for (int nt = 0; nt < 4; nt++) {
            int dd = 16 * nt + 4 * h;      // 4 consecutive d
            float4 b4 = *(const float4*)(bias + n0 + dd);
            float v0 = (acc[nt][0] + b4.x) * scl;
            float v1 = (acc[nt][1] + b4.y) * scl;
            float v2 = (acc[nt][2] + b4.z) * scl;
            float v3 = (acc[nt][3] + b4.w) * scl;
            u32x2 pk = {cvtpk(v0, v1), cvtpk(v2, v3)};
            *(u32x2*)&dst[rowoff + dd] = pk;
        }
    }
}

// ---------------------------------------------------------------------------
// Kernel B: attention v6 (unchanged from r9) — q-register-blocked, single
// kernel, grid 384 XCD-pinned, reg double-buffered loads.
// ---------------------------------------------------------------------------
__global__ __launch_bounds__(512, 2) void attn_kernel(
    const short* __restrict__ qh, const short* __restrict__ kh, const short* __restrict__ vt,
    float* __restrict__ attn, short* __restrict__ ctx)
{
    __shared__ float sml[4][2][2][16];
    __shared__ float olds[4][64][32];

    int wgid = blockIdx.x;
    int xcd = wgid & 7;
    int idx = wgid >> 3;
    int bh = xcd * 3 + (idx >> 4);
    int q0 = (idx & 15) * 128;

    int lane = threadIdx.x & 63, w = threadIdx.x >> 6;
    int wq2 = w >> 1, ksh = w & 1;
    int r = lane & 15, h = lane >> 4;
    int qbase = q0 + 32 * wq2;
    int kstart = ksh * (SEQ / 2), kend = kstart + SEQ / 2;

    const short* Qp = qh + ((long)bh * SEQ + qbase) * DEPTH;
    const short* Kp = kh + (long)bh * SEQ * DEPTH;
    const short* Vb = vt + (long)bh * (64 * DEPTH * 32);

    bf16x8 qf[2][2];
#pragma unroll
    for (int j = 0; j < 2; j++) {
        qf[j][0] = *(const bf16x8*)(Qp + (16 * j + r) * DEPTH + 8 * h);
        qf[j][1] = *(const bf16x8*)(Qp + (16 * j + r) * DEPTH + 32 + 8 * h);
    }

    // ---- pass 1: K-only, accumulate sum of exp2 per q-set ----
    float l0 = 0.f, l1 = 0.f;
    {
        KF kc_ = loadK(Kp, kstart, r, h);
        for (int k0 = kstart; k0 < kend; k0 += 32) {
            int kn = (k0 + 32 < kend) ? (k0 + 32) : kstart;
            KF kn_ = loadK(Kp, kn, r, h);
#pragma unroll
            for (int j = 0; j < 2; j++) {
                f32x4 s0 = {}, s1 = {};
                s0 = MFMA16(kc_.a0, qf[j][0], s0);
                s1 = MFMA16(kc_.b0, qf[j][0], s1);
                s0 = MFMA16(kc_.a1, qf[j][1], s0);
                s1 = MFMA16(kc_.b1, qf[j][1], s1);
                float sum = exp2f(s0[0]) + exp2f(s0[1]) + exp2f(s0[2]) + exp2f(s0[3])
                          + exp2f(s1[0]) + exp2f(s1[1]) + exp2f(s1[2]) + exp2f(s1[3]);
                if (j == 0) l0 += sum; else l1 += sum;
            }
            kc_ = kn_;
        }
    }
    l0 += __shfl_xor(l0, 16); l0 += __shfl_xor(l0, 32);
    l1 += __shfl_xor(l1, 16); l1 += __shfl_xor(l1, 32);
    if (lane < 16) {
        sml[wq2][ksh][0][lane] = l0;
        sml[wq2][ksh][1][lane] = l1;
    }
    __syncthreads();
    float rl[2];
#pragma unroll
    for (int j = 0; j < 2; j++)
        rl[j] = 1.0f / (sml[wq2][0][j][r] + sml[wq2][1][j][r]);

    // ---- pass 2: recompute QK, NT-store P, PV ----
    f32x4 o[2][4] = {};
    float* arow0 = attn + ((long)(bh * SEQ + qbase + r)) * SEQ;
    float* arow1 = attn + ((long)(bh * SEQ + qbase + 16 + r)) * SEQ;

    {
        KF kc_ = loadK(Kp, kstart, r, h);
        VF vc  = loadV(Vb, kstart, r, h);
        for (int k0 = kstart; k0 < kend; k0 += 32) {
            int kn = (k0 + 32 < kend) ? (k0 + 32) : kstart;
            KF kn_ = loadK(Kp, kn, r, h);
            VF vn  = loadV(Vb, kn, r, h);

#pragma unroll
            for (int j = 0; j < 2; j++) {
                f32x4 s0 = {}, s1 = {};
                s0 = MFMA16(kc_.a0, qf[j][0], s0);
                s1 = MFMA16(kc_.b0, qf[j][0], s1);
                s0 = MFMA16(kc_.a1, qf[j][1], s0);
                s1 = MFMA16(kc_.b1, qf[j][1], s1);

                float p0 = exp2f(s0[0]) * rl[j], p1 = exp2f(s0[1]) * rl[j];
                float p2 = exp2f(s0[2]) * rl[j], p3 = exp2f(s0[3]) * rl[j];
                float p4 = exp2f(s1[0]) * rl[j], p5 = exp2f(s1[1]) * rl[j];
                float p6 = exp2f(s1[2]) * rl[j], p7 = exp2f(s1[3]) * rl[j];

                f32x4 st0 = {p0, p1, p2, p3};
                f32x4 st1 = {p4, p5, p6, p7};
                float* arow = j ? arow1 : arow0;
                __builtin_nontemporal_store(st0, (f32x4*)(arow + k0 + 4 * h));
                __builtin_nontemporal_store(st1, (f32x4*)(arow + k0 + 16 + 4 * h));

                union { unsigned u[4]; bf16x8 v; } pa;
                pa.u[0] = cvtpk(p0, p1); pa.u[1] = cvtpk(p2, p3);
                pa.u[2] = cvtpk(p4, p5); pa.u[3] = cvtpk(p6, p7);

#pragma unroll
                for (int nt = 0; nt < 4; nt++) {
                    union { short4 s4[2]; bf16x8 v; } vf;
                    vf.s4[0] = vc.x[2 * nt];
                    vf.s4[1] = vc.x[2 * nt + 1];
                    o[j][nt] = MFMA16(vf.v, pa.v, o[j][nt]);
                }
            }
            kc_ = kn_;
            vc = vn;
        }
    }

    // ---- merge O across the two k-half waves, write ctx ----
    if (ksh == 1) {
#pragma unroll
        for (int j = 0; j < 2; j++)
#pragma unroll
            for (int nt = 0; nt < 4; nt++)
                *(f32x4*)&olds[wq2][lane][(j * 4 + nt) * 4] = o[j][nt];
    }
    __syncthreads();
    if (ksh == 0) {
        int b = bh / NHEADS, head = bh % NHEADS;
#pragma unroll
        for (int j = 0; j < 2; j++) {
            long crow = ((long)(b * SEQ + qbase + 16 * j + r)) * D_MODEL + head * DEPTH;
#pragma unroll
            for (int nt = 0; nt < 4; nt++) {
                f32x4 op = *(const f32x4*)&olds[wq2][lane][(j * 4 + nt) * 4];
                float v0 = o[j][nt][0] + op[0];
                float v1 = o[j][nt][1] + op[1];
                float v2 = o[j][nt][2] + op[2];
                float v3 = o[j][nt][3] + op[3];
                *(unsigned*)&ctx[crow + 16 * nt + 4 * h]     = cvtpk(v0, v1);
                *(unsigned*)&ctx[crow + 16 * nt + 4 * h + 2] = cvtpk(v2, v3);
            }
        }
    }
}

// ---------------------------------------------------------------------------
// Kernel C: output projection  out = ctx @ wo + bo  (fp32 out).
// SWAPPED operand order -> each lane holds 4 consecutive n -> float4 stores.
// ---------------------------------------------------------------------------
__global__ __launch_bounds__(256) void out_gemm(
    const short* __restrict__ ctx, const short* __restrict__ wt3,
    const float* __restrict__ bo, float* __restrict__ out)
{
    int m0 = blockIdx.x * 64, n0 = blockIdx.y * 64;
    int lane = threadIdx.x & 63, w = threadIdx.x >> 6;
    int r = lane & 15, h = lane >> 4;

    f32x4 acc[4] = {};
    const short* arow = ctx + (m0 + 16 * w + r) * D_MODEL;

    for (int k0 = 0; k0 < D_MODEL; k0 += 32) {
        bf16x8 af = *(const bf16x8*)(arow + k0 + 8 * h);
#pragma unroll
        for (int nt = 0; nt < 4; nt++) {
            bf16x8 bfr = *(const bf16x8*)(wt3 + (n0 + 16 * nt + r) * D_MODEL + k0 + 8 * h);
            acc[nt] = MFMA16(bfr, af, acc[nt]);   // SWAPPED: rows=n, cols=m
        }
    }
    int m = m0 + 16 * w + r;
#pragma unroll
    for (int nt = 0; nt < 4; nt++) {
        int n = n0 + 16 * nt + 4 * h;             // 4 consecutive n
        float4 b4 = *(const float4*)(bo + n);
        f32x4 res = {acc[nt][0] + b4.x, acc[nt][1] + b4.y,
                     acc[nt][2] + b4.z, acc[nt][3] + b4.w};
        *(f32x4*)(out + (long)m * D_MODEL + n) = res;
    }
}

// ---------------------------------------------------------------------------
extern "C" void kernel_launch(void* const* d_in, const int* in_sizes, int n_in,
                              void* d_out, int out_size, void* d_ws, size_t ws_size,
                              hipStream_t stream)
{
    const float* v  = (const float*)d_in[0];
    const float* k  = (const float*)d_in[1];
    const float* q  = (const float*)d_in[2];
    const float* wq = (const float*)d_in[3];
    const float* bq = (const float*)d_in[4];
    const float* wk = (const float*)d_in[5];
    const float* bk = (const float*)d_in[6];
    const float* wv = (const float*)d_in[7];
    const float* bv = (const float*)d_in[8];
    const float* wo = (const float*)d_in[9];
    const float* bo = (const float*)d_in[10];

    char* ws = (char*)d_ws;
    const size_t WT_BYTES  = (size_t)4 * D_MODEL * D_MODEL * 2;    // 4.7 MB
    const size_t XB_BYTES  = (size_t)3 * NROWS * D_MODEL * 2;      // 18.9 MB
    const size_t HB_BYTES  = (size_t)2 * NHEADS * SEQ * DEPTH * 2; // 6.3 MB
    short* wt  = (short*)(ws);
    short* xb  = (short*)(ws + WT_BYTES);
    short* qh  = (short*)(ws + WT_BYTES + XB_BYTES);
    short* kh  = (short*)(ws + WT_BYTES + XB_BYTES + HB_BYTES);
    short* vt  = (short*)(ws + WT_BYTES + XB_BYTES + 2 * HB_BYTES);
    short* ctx = (short*)(ws + WT_BYTES + XB_BYTES + 3 * HB_BYTES);

    float* out  = (float*)d_out;
    float* attn = (float*)d_out + (size_t)NROWS * D_MODEL;

    xcast_kernel<<<dim3(1536, 3), dim3(256), 0, stream>>>(q, k, v, xb);
    wtrans_kernel<<<dim3(24, 24, 4), dim3(256), 0, stream>>>(wq, wk, wv, wo, wt);
    qkv_gemm<<<dim3(64, 12, 3), dim3(256), 0, stream>>>(xb, wt, bq, bk, bv, qh, kh, vt);
    attn_kernel<<<dim3(384), dim3(512), 0, stream>>>(qh, kh, vt, attn, ctx);
    out_gemm<<<dim3(64, 12), dim3(256), 0, stream>>>(ctx, wt + 3 * D_MODEL * D_MODEL, bo, out);
}